// Round 1
// baseline (4834.320 us; speedup 1.0000x reference)
//
#include <hip/hip_runtime.h>
#include <hip/hip_bf16.h>

#define N_CELLS  512
#define N_PIX    25600
#define NBF      100      // n_bins_filter
#define MAXC     20
#define N_FRAMES 300
#define NBT      1500     // n_bins_total
#define N_INIT   100
#define T_STEPS  (NBT - N_INIT)   // 1400

#define RING 104
#define NWG  64
#define CPW  (N_CELLS / NWG)      // 8 cells per WG
#define SCAN_THREADS (CPW * 64)   // 512
#define FLAG_STRIDE 32            // ints -> 128B per flag line

// ---------------- GEMM tiling ----------------
#define GT 64
#define GC 64
#define GK 64
#define KSPLIT 8
#define KCH (N_PIX / KSPLIT)      // 3200

// ============== init flags ==============
__global__ void init_flags_k(int* flags) {
    int i = blockIdx.x * 256 + threadIdx.x;
    if (i < NWG * FLAG_STRIDE) flags[i] = 0;
}

// ============== GEMM partial: part[kb][t][c] = sum_{k in chunk} A[t,k]*B[c,k] ==============
__global__ __launch_bounds__(256) void gemm_partial_k(
        const float* __restrict__ A,   // input_frames [300][25600]
        const float* __restrict__ B,   // spat_filters [512][25600]
        float* __restrict__ part)      // [KSPLIT][300][512]
{
    __shared__ float As[GK][GT + 4];   // transposed: [k][row], padded for b128
    __shared__ float Bs[GK][GC + 4];
    const int kb = blockIdx.x, tb = blockIdx.y, cb = blockIdx.z;
    const int tid = threadIdx.x;
    const int tx = tid & 15, ty = tid >> 4;
    const int t0 = tb * GT, c0 = cb * GC, k0 = kb * KCH;

    float acc[4][4];
    #pragma unroll
    for (int i = 0; i < 4; ++i)
        #pragma unroll
        for (int j = 0; j < 4; ++j) acc[i][j] = 0.f;

    for (int kc = 0; kc < KCH; kc += GK) {
        #pragma unroll
        for (int p = 0; p < 4; ++p) {
            const int r  = (tid >> 4) + p * 16;
            const int kk = (tid & 15) * 4;
            float4 av = make_float4(0.f, 0.f, 0.f, 0.f);
            if (t0 + r < N_FRAMES)
                av = *(const float4*)&A[(size_t)(t0 + r) * N_PIX + k0 + kc + kk];
            As[kk + 0][r] = av.x; As[kk + 1][r] = av.y;
            As[kk + 2][r] = av.z; As[kk + 3][r] = av.w;
            const float4 bv = *(const float4*)&B[(size_t)(c0 + r) * N_PIX + k0 + kc + kk];
            Bs[kk + 0][r] = bv.x; Bs[kk + 1][r] = bv.y;
            Bs[kk + 2][r] = bv.z; Bs[kk + 3][r] = bv.w;
        }
        __syncthreads();
        #pragma unroll
        for (int kk = 0; kk < GK; ++kk) {
            const float4 a4 = *(const float4*)&As[kk][ty * 4];
            const float4 b4 = *(const float4*)&Bs[kk][tx * 4];
            const float aa[4] = {a4.x, a4.y, a4.z, a4.w};
            const float bb[4] = {b4.x, b4.y, b4.z, b4.w};
            #pragma unroll
            for (int ii = 0; ii < 4; ++ii)
                #pragma unroll
                for (int jj = 0; jj < 4; ++jj)
                    acc[ii][jj] = fmaf(aa[ii], bb[jj], acc[ii][jj]);
        }
        __syncthreads();
    }
    #pragma unroll
    for (int ii = 0; ii < 4; ++ii) {
        const int t = t0 + ty * 4 + ii;
        if (t < N_FRAMES) {
            #pragma unroll
            for (int jj = 0; jj < 4; ++jj)
                part[(size_t)kb * (N_FRAMES * N_CELLS) + (size_t)t * N_CELLS + c0 + tx * 4 + jj] = acc[ii][jj];
        }
    }
}

// ============== reduce split-K partials ==============
__global__ void reduce_part_k(const float* __restrict__ part, float* __restrict__ spat) {
    int i = blockIdx.x * 256 + threadIdx.x;
    if (i < N_FRAMES * N_CELLS) {
        float s = 0.f;
        #pragma unroll
        for (int kb = 0; kb < KSPLIT; ++kb) s += part[(size_t)kb * (N_FRAMES * N_CELLS) + i];
        spat[i] = s;
    }
}

// ============== stim[t][c] = bias[c] + sum_k fw[t,k]*spat[fs[t,k]][c] ==============
__global__ void stim_k(const float* __restrict__ spat, const float* __restrict__ bias,
                       const float* __restrict__ fw, const int* __restrict__ fs,
                       float* __restrict__ stimb) {
    int i = blockIdx.x * 256 + threadIdx.x;
    if (i < NBT * N_CELLS) {
        const int t = i >> 9, c = i & (N_CELLS - 1);
        const int t2 = t * 2;
        float v = bias[c];
        v = fmaf(fw[t2],     spat[(size_t)fs[t2]     * N_CELLS + c], v);
        v = fmaf(fw[t2 + 1], spat[(size_t)fs[t2 + 1] * N_CELLS + c], v);
        stimb[i] = v;
    }
}

// ============== copy initial spikes into out[c][0..99] ==============
__global__ void copy_init_k(const float* __restrict__ ini, float* __restrict__ out) {
    int i = blockIdx.x * 256 + threadIdx.x;
    if (i < N_CELLS * N_INIT) {
        const int c = i / N_INIT;
        const int j = i - c * N_INIT;
        out[(size_t)c * NBT + j] = ini[i];
    }
}

// ============== persistent scan: 64 WGs, wave-per-cell, flag-synced ==============
__global__ __launch_bounds__(SCAN_THREADS) void scan_k(
        const float* __restrict__ stimb,  // [1500][512]
        const float* __restrict__ cf,     // [512][20][100]
        const float* __restrict__ ff,     // [512][100]
        const int*   __restrict__ sel,    // [512][20]
        const float* __restrict__ ini,    // [512][100]
        float* __restrict__ X,            // [1400][512] exchange
        int*   __restrict__ flags,        // [NWG*FLAG_STRIDE]
        float* __restrict__ out)          // [512][1500]
{
    __shared__ __hip_bfloat16 win[N_CELLS][RING];   // full spike-history ring, all cells
    __shared__ float stage[CPW];

    const int wg   = blockIdx.x;
    const int tid  = threadIdx.x;
    const int wave = tid >> 6;
    const int lane = tid & 63;
    const int cell = wg * CPW + wave;

    // ---- per-lane static coefficients: lane <-> lag (lag1 = lane+1, lag2 = lane+65) ----
    int   srcm[MAXC + 1];
    float c1v[MAXC + 1], c2v[MAXC + 1];
    const int l1 = lane + 1;
    const int l2 = lane + 65;
    #pragma unroll
    for (int m = 0; m <= MAXC; ++m) {
        const int s = (m < MAXC) ? sel[cell * MAXC + m] : cell;
        const float* f = (m < MAXC) ? (cf + (size_t)(cell * MAXC + m) * NBF)
                                    : (ff + (size_t)cell * NBF);
        srcm[m] = s;
        c1v[m]  = f[NBF - l1];                       // lag 1..64 -> idx 99..36
        c2v[m]  = (l2 <= NBF) ? f[NBF - l2] : 0.f;   // lag 65..100 -> idx 35..0, else 0
    }

    // ---- window init: zero ring, then initial spikes at times -100..-1 ----
    {
        __hip_bfloat16* wf = &win[0][0];
        for (int i = tid; i < N_CELLS * RING; i += SCAN_THREADS) wf[i] = __float2bfloat16(0.f);
        __syncthreads();
        for (int i = tid; i < N_CELLS * N_INIT; i += SCAN_THREADS) {
            const int c = i / N_INIT;
            const int b = i - c * N_INIT;
            const int tau = b - N_INIT;                          // -100..-1
            const int slot = ((tau % RING) + RING) % RING;
            win[c][slot] = __float2bfloat16(ini[i]);
        }
    }
    __syncthreads();

    int slot1 = ((-(l1)) % RING + RING) % RING;  // slot(time -lag1) at i=0
    int slot2 = ((-(l2)) % RING + RING) % RING;
    int slotw = RING - 1;                        // slot(i-1) used from i=1

    for (int i = 0; i < T_STEPS; ++i) {
        const float stim_v = (lane == 0) ? stimb[(size_t)(N_INIT - 1 + i) * N_CELLS + cell] : 0.f;

        if (i > 0) {
            if (wave == 0) {
                // lane w waits until WG w has posted step i-1
                while (__hip_atomic_load(&flags[lane * FLAG_STRIDE], __ATOMIC_ACQUIRE,
                                         __HIP_MEMORY_SCOPE_AGENT) < i) {
                    __builtin_amdgcn_s_sleep(1);
                }
            }
            __syncthreads();
            // pull all 512 spikes of time i-1 (coherent bypass loads) into the ring
            const float v = __hip_atomic_load(&X[(size_t)(i - 1) * N_CELLS + tid],
                                              __ATOMIC_RELAXED, __HIP_MEMORY_SCOPE_AGENT);
            win[tid][slotw] = __float2bfloat16(v);
            __syncthreads();
        }

        // ---- gensig for this wave's cell ----
        float acc = 0.f;
        #pragma unroll
        for (int m = 0; m <= MAXC; ++m) {
            const float w1 = __bfloat162float(win[srcm[m]][slot1]);
            const float w2 = __bfloat162float(win[srcm[m]][slot2]);
            acc = fmaf(w1, c1v[m], acc);
            acc = fmaf(w2, c2v[m], acc);
        }
        #pragma unroll
        for (int off = 32; off > 0; off >>= 1) acc += __shfl_xor(acc, off, 64);

        if (lane == 0) {
            const float g = stim_v + acc;
            const float s = 1.f / (1.f + __expf(-g));
            stage[wave] = s;
            out[(size_t)cell * NBT + N_INIT + i] = s;
        }
        __syncthreads();

        if (tid == 0) {
            #pragma unroll
            for (int k = 0; k < CPW; ++k)
                __hip_atomic_store(&X[(size_t)i * N_CELLS + wg * CPW + k], stage[k],
                                   __ATOMIC_RELAXED, __HIP_MEMORY_SCOPE_AGENT);
            __hip_atomic_store(&flags[wg * FLAG_STRIDE], i + 1,
                               __ATOMIC_RELEASE, __HIP_MEMORY_SCOPE_AGENT);
        }

        slot1 = (slot1 + 1 == RING) ? 0 : slot1 + 1;
        slot2 = (slot2 + 1 == RING) ? 0 : slot2 + 1;
        slotw = (slotw + 1 == RING) ? 0 : slotw + 1;
    }
}

extern "C" void kernel_launch(void* const* d_in, const int* in_sizes, int n_in,
                              void* d_out, int out_size, void* d_ws, size_t ws_size,
                              hipStream_t stream) {
    const float* ini    = (const float*)d_in[0];   // initial_spikes [512][100]
    const float* frames = (const float*)d_in[1];   // input_frames  [300][25600]
    const float* sfil   = (const float*)d_in[2];   // spat_filters  [512][25600]
    const float* ff     = (const float*)d_in[3];   // feedback_filters [512][100]
    const float* cf     = (const float*)d_in[4];   // coupling_filters [512][20][100]
    const float* bias   = (const float*)d_in[5];   // [512][1]
    const float* fw     = (const float*)d_in[6];   // forward_weights [1500][2]
    const int*   sel    = (const int*)d_in[7];     // coupled_sel [512][20]
    const int*   fs     = (const int*)d_in[8];     // forward_sel [1500][2]
    float* out = (float*)d_out;
    float* ws  = (float*)d_ws;

    // ws layout (floats): spat | stimb | X | flags ; GEMM partials overlap stimb+X (dead after reduce)
    float* spat  = ws;                                     // 153600
    float* stimb = ws + 153600;                            // 768000
    float* X     = ws + 153600 + 768000;                   // 716800
    int*   flags = (int*)(ws + 153600 + 768000 + 716800);  // 2048 ints
    float* part  = ws + 153600;                            // KSPLIT*153600 scratch

    hipLaunchKernelGGL(init_flags_k, dim3((NWG * FLAG_STRIDE + 255) / 256), dim3(256), 0, stream, flags);
    hipLaunchKernelGGL(gemm_partial_k,
                       dim3(KSPLIT, (N_FRAMES + GT - 1) / GT, N_CELLS / GC), dim3(256), 0, stream,
                       frames, sfil, part);
    hipLaunchKernelGGL(reduce_part_k, dim3((N_FRAMES * N_CELLS + 255) / 256), dim3(256), 0, stream, part, spat);
    hipLaunchKernelGGL(stim_k, dim3((NBT * N_CELLS + 255) / 256), dim3(256), 0, stream, spat, bias, fw, fs, stimb);
    hipLaunchKernelGGL(copy_init_k, dim3((N_CELLS * N_INIT + 255) / 256), dim3(256), 0, stream, ini, out);
    hipLaunchKernelGGL(scan_k, dim3(NWG), dim3(SCAN_THREADS), 0, stream,
                       stimb, cf, ff, sel, ini, X, flags, out);
}

// Round 2
// 2235.808 us; speedup vs baseline: 2.1622x; 2.1622x over previous
//
#include <hip/hip_runtime.h>
#include <hip/hip_bf16.h>

#define N_CELLS  512
#define N_PIX    25600
#define NBF      100      // n_bins_filter
#define MAXC     20
#define N_FRAMES 300
#define NBT      1500     // n_bins_total
#define N_INIT   100
#define T_STEPS  (NBT - N_INIT)   // 1400

#define RING   104        // logical ring (time mod RING)
#define RSTR   105        // LDS storage stride (odd -> conflict-free column writes)
#define NWG    64
#define CPW    (N_CELLS / NWG)    // 8 cells per WG
#define SCAN_THREADS (CPW * 64)   // 512
#define XDEPTH 8                  // exchange ring depth (producer lead <= ~2)

// ---------------- GEMM tiling ----------------
#define GT 64
#define GC 64
#define GK 64
#define KSPLIT 8
#define KCH (N_PIX / KSPLIT)      // 3200

// ============== GEMM partial: part[kb][t][c] = sum_{k in chunk} A[t,k]*B[c,k] ==============
__global__ __launch_bounds__(256) void gemm_partial_k(
        const float* __restrict__ A,   // input_frames [300][25600]
        const float* __restrict__ B,   // spat_filters [512][25600]
        float* __restrict__ part)      // [KSPLIT][300][512]
{
    __shared__ float As[GK][GT + 4];   // transposed: [k][row]
    __shared__ float Bs[GK][GC + 4];
    const int kb = blockIdx.x, tb = blockIdx.y, cb = blockIdx.z;
    const int tid = threadIdx.x;
    const int tx = tid & 15, ty = tid >> 4;
    const int t0 = tb * GT, c0 = cb * GC, k0 = kb * KCH;

    float acc[4][4];
    #pragma unroll
    for (int i = 0; i < 4; ++i)
        #pragma unroll
        for (int j = 0; j < 4; ++j) acc[i][j] = 0.f;

    for (int kc = 0; kc < KCH; kc += GK) {
        #pragma unroll
        for (int p = 0; p < 4; ++p) {
            const int r  = (tid >> 4) + p * 16;
            const int kk = (tid & 15) * 4;
            float4 av = make_float4(0.f, 0.f, 0.f, 0.f);
            if (t0 + r < N_FRAMES)
                av = *(const float4*)&A[(size_t)(t0 + r) * N_PIX + k0 + kc + kk];
            As[kk + 0][r] = av.x; As[kk + 1][r] = av.y;
            As[kk + 2][r] = av.z; As[kk + 3][r] = av.w;
            const float4 bv = *(const float4*)&B[(size_t)(c0 + r) * N_PIX + k0 + kc + kk];
            Bs[kk + 0][r] = bv.x; Bs[kk + 1][r] = bv.y;
            Bs[kk + 2][r] = bv.z; Bs[kk + 3][r] = bv.w;
        }
        __syncthreads();
        #pragma unroll
        for (int kk = 0; kk < GK; ++kk) {
            const float4 a4 = *(const float4*)&As[kk][ty * 4];
            const float4 b4 = *(const float4*)&Bs[kk][tx * 4];
            const float aa[4] = {a4.x, a4.y, a4.z, a4.w};
            const float bb[4] = {b4.x, b4.y, b4.z, b4.w};
            #pragma unroll
            for (int ii = 0; ii < 4; ++ii)
                #pragma unroll
                for (int jj = 0; jj < 4; ++jj)
                    acc[ii][jj] = fmaf(aa[ii], bb[jj], acc[ii][jj]);
        }
        __syncthreads();
    }
    #pragma unroll
    for (int ii = 0; ii < 4; ++ii) {
        const int t = t0 + ty * 4 + ii;
        if (t < N_FRAMES) {
            #pragma unroll
            for (int jj = 0; jj < 4; ++jj)
                part[(size_t)kb * (N_FRAMES * N_CELLS) + (size_t)t * N_CELLS + c0 + tx * 4 + jj] = acc[ii][jj];
        }
    }
}

// ============== reduce split-K partials ==============
__global__ void reduce_part_k(const float* __restrict__ part, float* __restrict__ spat) {
    int i = blockIdx.x * 256 + threadIdx.x;
    if (i < N_FRAMES * N_CELLS) {
        float s = 0.f;
        #pragma unroll
        for (int kb = 0; kb < KSPLIT; ++kb) s += part[(size_t)kb * (N_FRAMES * N_CELLS) + i];
        spat[i] = s;
    }
}

// ============== stim[t][c] = bias[c] + sum_k fw[t,k]*spat[fs[t,k]][c] ==============
__global__ void stim_k(const float* __restrict__ spat, const float* __restrict__ bias,
                       const float* __restrict__ fw, const int* __restrict__ fs,
                       float* __restrict__ stimb) {
    int i = blockIdx.x * 256 + threadIdx.x;
    if (i < NBT * N_CELLS) {
        const int t = i >> 9, c = i & (N_CELLS - 1);
        const int t2 = t * 2;
        float v = bias[c];
        v = fmaf(fw[t2],     spat[(size_t)fs[t2]     * N_CELLS + c], v);
        v = fmaf(fw[t2 + 1], spat[(size_t)fs[t2 + 1] * N_CELLS + c], v);
        stimb[i] = v;
    }
}

// ============== copy initial spikes into out[c][0..99] ==============
__global__ void copy_init_k(const float* __restrict__ ini, float* __restrict__ out) {
    int i = blockIdx.x * 256 + threadIdx.x;
    if (i < N_CELLS * N_INIT) {
        const int c = i / N_INIT;
        const int j = i - c * N_INIT;
        out[(size_t)c * NBT + j] = ini[i];
    }
}

__device__ __forceinline__ int wrap_slot(int t) {
    int s = t % RING;
    return (s < 0) ? s + RING : s;
}

// ============== persistent scan: 64 WGs, wave-per-cell, tagged-word exchange ==============
__global__ __launch_bounds__(SCAN_THREADS) void scan_k(
        const float* __restrict__ stimb,  // [1500][512]
        const float* __restrict__ cf,     // [512][20][100]
        const float* __restrict__ ff,     // [512][100]
        const int*   __restrict__ sel,    // [512][20]
        const float* __restrict__ ini,    // [512][100]
        unsigned long long* __restrict__ X64,  // [XDEPTH][512] tagged exchange
        float* __restrict__ out)          // [512][1500]
{
    __shared__ __hip_bfloat16 win[N_CELLS][RSTR];   // spike-history ring, all cells
    __shared__ float newspike[N_CELLS];             // f32 spikes of time i-1
    __shared__ int   lag1src[CPW][32];
    __shared__ float lag1coef[CPW][32];

    const int wg   = blockIdx.x;
    const int tid  = threadIdx.x;
    const int wave = tid >> 6;
    const int lane = tid & 63;
    const int cell = wg * CPW + wave;

    // ---- per-lane static coefficients for the lag>=2 partial:
    //      lane -> lag lane+2 (c1v) and lag lane+66 (c2v, lane<=34) ----
    int   srcm[MAXC + 1];
    float c1v[MAXC + 1], c2v[MAXC + 1];
    #pragma unroll
    for (int m = 0; m <= MAXC; ++m) {
        const int s = (m < MAXC) ? sel[cell * MAXC + m] : cell;
        const float* f = (m < MAXC) ? (cf + (size_t)(cell * MAXC + m) * NBF)
                                    : (ff + (size_t)cell * NBF);
        srcm[m] = s;
        c1v[m]  = f[98 - lane];                        // lag lane+2 -> idx 98..35
        c2v[m]  = (lane <= 34) ? f[34 - lane] : 0.f;   // lag lane+66 -> idx 34..0
        if (lane == m) {                               // lag-1 tables (static index)
            lag1src[wave][m]  = s;
            lag1coef[wave][m] = f[NBF - 1];
        }
    }

    // ---- window init: zero ring, then initial spikes at times -100..-1 ----
    {
        __hip_bfloat16* wf = &win[0][0];
        for (int i = tid; i < N_CELLS * RSTR; i += SCAN_THREADS) wf[i] = __float2bfloat16(0.f);
        __syncthreads();
        for (int i = tid; i < N_CELLS * N_INIT; i += SCAN_THREADS) {
            const int c = i / N_INIT;
            const int b = i - c * N_INIT;
            win[c][wrap_slot(b - N_INIT)] = __float2bfloat16(ini[i]);
        }
    }
    __syncthreads();

    // slots for the partial (lags >=2) of the NEXT step to be computed:
    // pre-loop computes partial for step 0: lag lane+2 -> time -(lane+2)
    int slotp1 = wrap_slot(-2 - lane);
    int slotp2 = wrap_slot(-66 - lane);
    int slotw  = RING - 1;                 // slot(time i-1) at iteration i (i=0 -> slot(-1)=103)

    const float ini_last = ini[tid * N_INIT + (N_INIT - 1)];   // y_{-1}[tid]

    float stim_next = 0.f;
    if (lane == 0) stim_next = stimb[(size_t)(N_INIT - 1) * N_CELLS + cell];

    // partial_0 (lags 2..100 of step 0)
    float partial;
    {
        float p = 0.f;
        #pragma unroll
        for (int m = 0; m <= MAXC; ++m) {
            const float w1 = __bfloat162float(win[srcm[m]][slotp1]);
            const float w2 = __bfloat162float(win[srcm[m]][slotp2]);
            p = fmaf(w1, c1v[m], p);
            p = fmaf(w2, c2v[m], p);
        }
        #pragma unroll
        for (int off = 32; off > 0; off >>= 1) p += __shfl_xor(p, off, 64);
        partial = p;
    }

    for (int i = 0; i < T_STEPS; ++i) {
        // ---- 1. obtain y_{i-1}[tid] ----
        float val;
        if (i > 0) {
            const unsigned long long* wp = &X64[(size_t)((i - 1) & (XDEPTH - 1)) * N_CELLS + tid];
            unsigned long long w;
            do {
                w = __hip_atomic_load(wp, __ATOMIC_RELAXED, __HIP_MEMORY_SCOPE_AGENT);
            } while ((unsigned)(w >> 32) != (unsigned)i);
            val = __uint_as_float((unsigned)w);
        } else {
            val = ini_last;
        }

        // ---- 2. publish to LDS ----
        newspike[tid] = val;
        win[tid][slotw] = __float2bfloat16(val);
        __syncthreads();

        // ---- 3. critical lag-1 terms + sigmoid + post ----
        float term = 0.f;
        if (lane <= MAXC) {
            term = newspike[lag1src[wave][lane]] * lag1coef[wave][lane];
        }
        #pragma unroll
        for (int off = 32; off > 0; off >>= 1) term += __shfl_xor(term, off, 64);

        if (lane == 0) {
            const float g = stim_next + partial + term;
            const float sp = 1.f / (1.f + __expf(-g));
            const unsigned long long pw =
                ((unsigned long long)(unsigned)(i + 1) << 32) |
                (unsigned long long)__float_as_uint(sp);
            __hip_atomic_store(&X64[(size_t)(i & (XDEPTH - 1)) * N_CELLS + cell], pw,
                               __ATOMIC_RELAXED, __HIP_MEMORY_SCOPE_AGENT);
            out[(size_t)cell * NBT + N_INIT + i] = sp;
        }

        // ---- 4. advance slots; compute partial for step i+1 (hidden under exchange) ----
        slotw  = (slotw  + 1 == RING) ? 0 : slotw  + 1;
        slotp1 = (slotp1 + 1 == RING) ? 0 : slotp1 + 1;
        slotp2 = (slotp2 + 1 == RING) ? 0 : slotp2 + 1;

        if (lane == 0 && i + 1 < T_STEPS)
            stim_next = stimb[(size_t)(N_INIT + i) * N_CELLS + cell];

        float p = 0.f;
        #pragma unroll
        for (int m = 0; m <= MAXC; ++m) {
            const float w1 = __bfloat162float(win[srcm[m]][slotp1]);
            const float w2 = __bfloat162float(win[srcm[m]][slotp2]);
            p = fmaf(w1, c1v[m], p);
            p = fmaf(w2, c2v[m], p);
        }
        #pragma unroll
        for (int off = 32; off > 0; off >>= 1) p += __shfl_xor(p, off, 64);
        partial = p;
    }
}

extern "C" void kernel_launch(void* const* d_in, const int* in_sizes, int n_in,
                              void* d_out, int out_size, void* d_ws, size_t ws_size,
                              hipStream_t stream) {
    const float* ini    = (const float*)d_in[0];   // initial_spikes [512][100]
    const float* frames = (const float*)d_in[1];   // input_frames  [300][25600]
    const float* sfil   = (const float*)d_in[2];   // spat_filters  [512][25600]
    const float* ff     = (const float*)d_in[3];   // feedback_filters [512][100]
    const float* cf     = (const float*)d_in[4];   // coupling_filters [512][20][100]
    const float* bias   = (const float*)d_in[5];   // [512][1]
    const float* fw     = (const float*)d_in[6];   // forward_weights [1500][2]
    const int*   sel    = (const int*)d_in[7];     // coupled_sel [512][20]
    const int*   fs     = (const int*)d_in[8];     // forward_sel [1500][2]
    float* out = (float*)d_out;
    float* ws  = (float*)d_ws;

    // ws layout (floats):
    //   spat  @ 0                (153600)
    //   stimb @ 153600           (768000)
    //   X64   @ 921600           (XDEPTH*512 u64 = 8192 floats)
    //   part  @ 153600           (KSPLIT*153600 = 1228800, overlaps stimb+X64; dead after reduce)
    float* spat  = ws;
    float* stimb = ws + 153600;
    unsigned long long* X64 = (unsigned long long*)(ws + 153600 + 768000);
    float* part  = ws + 153600;

    hipLaunchKernelGGL(gemm_partial_k,
                       dim3(KSPLIT, (N_FRAMES + GT - 1) / GT, N_CELLS / GC), dim3(256), 0, stream,
                       frames, sfil, part);
    hipLaunchKernelGGL(reduce_part_k, dim3((N_FRAMES * N_CELLS + 255) / 256), dim3(256), 0, stream, part, spat);
    hipLaunchKernelGGL(stim_k, dim3((NBT * N_CELLS + 255) / 256), dim3(256), 0, stream, spat, bias, fw, fs, stimb);
    hipMemsetAsync(X64, 0, (size_t)XDEPTH * N_CELLS * sizeof(unsigned long long), stream);
    hipLaunchKernelGGL(copy_init_k, dim3((N_CELLS * N_INIT + 255) / 256), dim3(256), 0, stream, ini, out);
    hipLaunchKernelGGL(scan_k, dim3(NWG), dim3(SCAN_THREADS), 0, stream,
                       stimb, cf, ff, sel, ini, X64, out);
}